// Round 2
// baseline (481.463 us; speedup 1.0000x reference)
//
#include <hip/hip_runtime.h>

// N=1024, F_NODE=64, F_EDGE=32, F_IN=160.
// out[a,j] = sum_b gated(a,b,j);  gated = relu(Hp)*sigmoid(Ha)
// Hp[a,b,j] = A[a,b]*(H[a]·W[0:64,j] + H[b]·W[64:128,j] + E[a,b]·W[128:160,j]) + bias[j]
// A in {0,1}: A=0 pairs contribute g0[j]=relu(bias)*sigmoid(bias) (constant).
//
// R10 (this round): software-pipeline the gather loop.
//  - R9's loop issued next-chunk loads with ZERO lookahead -> ~900cy cold
//    stall every 128 rows (load duty cycle ~50%, E stream under-saturated).
//    Now: 64-row sub granularity, 2 register buffers, issue-after-consume:
//    every sub's loads are in flight one full compsub before consumption.
//  - s_setprio(1) around the MFMA clusters: loop is barrier-free, 12
//    independent waves/CU at different phases (attn-like regime where
//    setprio measured +4-7%; null only in lockstep-barrier GEMM).
//  - Everything else (inline compact, MFMA structure, reduction) unchanged.
#define NN 1024
#define FN 64
#define FE 32
#define FIN 160

typedef __bf16 bf16x8 __attribute__((ext_vector_type(8)));
typedef short  short8 __attribute__((ext_vector_type(8)));
typedef float  f32x4  __attribute__((ext_vector_type(4)));

static __device__ __forceinline__ unsigned short f2b(float x){
    unsigned int u = __float_as_uint(x);
    unsigned int r = (u + 0x7fffu + ((u >> 16) & 1u)) >> 16;
    return (unsigned short)r;
}

static __device__ __forceinline__ float fast_sigmoid(float y){
    return __builtin_amdgcn_rcpf(1.0f + __expf(-y));
}

static __device__ __forceinline__ bf16x8 ldfrag(const unsigned short* p){
    return __builtin_bit_cast(bf16x8, *(const short8*)(p));
}

// pack two f32 -> (bf16 lo, bf16 hi) by truncation: one v_perm_b32
static __device__ __forceinline__ unsigned packtrunc(float lo, float hi){
    return __builtin_amdgcn_perm(__float_as_uint(hi), __float_as_uint(lo), 0x07060302u);
}

// blocks 0..63: H f32 -> Hb bf16 (1024x64); block 64/65: W/Wa -> Wt[j][k] bf16
__global__ void prep(const float* __restrict__ H, const float* __restrict__ W,
                     const float* __restrict__ Wa,
                     unsigned short* __restrict__ Hb,
                     unsigned short* __restrict__ WtE,
                     unsigned short* __restrict__ WtA){
    int bid = blockIdx.x, tid = threadIdx.x;
    if (bid < 64){
        int i = (bid*256 + tid)*4;
        float4 v = *(const float4*)(H + i);
        ushort4 o;
        o.x = f2b(v.x); o.y = f2b(v.y); o.z = f2b(v.z); o.w = f2b(v.w);
        *(ushort4*)(Hb + i) = o;
    } else {
        const float* src = (bid == 64) ? W : Wa;
        unsigned short* dst = (bid == 64) ? WtE : WtA;
        for (int idx = tid; idx < FIN*FN; idx += 256){
            int k = idx >> 6, j = idx & 63;
            dst[j*FIN + k] = f2b(src[idx]);
        }
    }
}

// One block per row a. Inline compaction (order-preserving shuffle scan into
// LDS), then the pipelined MFMA loop over the compacted list, then direct
// out[a,:] write including the (N-c1)*g0 constant term.
// 4 waves, wave=(half<<1)|mh: half -> j-tiles {2half,2half+1}, mh -> 32-row
// half of each 64-row sub-chunk.
// mfma_f32_16x16x32_bf16: A[m=lane&15][k=quad*8+i], B[k][n=lane&15],
// D: col=lane&15, row=quad*4+reg  [measured m89/m91].
__global__ __launch_bounds__(256, 3) void mga_fused(
    const float* __restrict__ A,
    const float* __restrict__ E,
    const unsigned short* __restrict__ Hb,
    const unsigned short* __restrict__ WtE, const unsigned short* __restrict__ WtA,
    const float* __restrict__ bias, float* __restrict__ out)
{
    int a    = blockIdx.x;
    int tid  = threadIdx.x;
    int wave = tid >> 6, lane = tid & 63;
    int col  = lane & 15, quad = lane >> 4;
    int half = wave >> 1, mh = wave & 1;

    __shared__ unsigned short lidx[NN];    // compacted b-indices, sorted
    __shared__ float red[16*FN];
    __shared__ int wsum[4];

    // ---- issue A-row load first: latency hides under B-frags + init MFMAs
    int b0 = wave*256 + lane*4;
    float4 av = *(const float4*)(A + (size_t)a*NN + b0);

    // Held B-frags: k-segs {64..96,96..128,128..160} x 2 j-tiles x 2 mats
    bf16x8 Bw[2][3], Ba[2][3];
    #pragma unroll
    for (int tl = 0; tl < 2; tl++){
        int n = (2*half + tl)*16 + col;
        #pragma unroll
        for (int sg = 0; sg < 3; sg++){
            Bw[tl][sg] = ldfrag(WtE + n*FIN + (sg+2)*32 + quad*8);
            Ba[tl][sg] = ldfrag(WtA + n*FIN + (sg+2)*32 + quad*8);
        }
    }

    // Upfront c-init = bias[j] + H[a]·W[0:64,j] via broadcast-A MFMAs
    bf16x8 ha0 = ldfrag(Hb + a*FN + quad*8);
    bf16x8 ha1 = ldfrag(Hb + a*FN + 32 + quad*8);
    f32x4 cw[2], ca[2];
    float acc[2] = {0.f, 0.f};
    #pragma unroll
    for (int tl = 0; tl < 2; tl++){
        int n = (2*half + tl)*16 + col;
        float bj = bias[n];
        f32x4 cb = {bj, bj, bj, bj};
        bf16x8 w0 = ldfrag(WtE + n*FIN + quad*8);
        bf16x8 w1 = ldfrag(WtE + n*FIN + 32 + quad*8);
        cw[tl] = __builtin_amdgcn_mfma_f32_16x16x32_bf16(ha1, w1,
                 __builtin_amdgcn_mfma_f32_16x16x32_bf16(ha0, w0, cb, 0,0,0), 0,0,0);
        w0 = ldfrag(WtA + n*FIN + quad*8);
        w1 = ldfrag(WtA + n*FIN + 32 + quad*8);
        ca[tl] = __builtin_amdgcn_mfma_f32_16x16x32_bf16(ha1, w1,
                 __builtin_amdgcn_mfma_f32_16x16x32_bf16(ha0, w0, cb, 0,0,0), 0,0,0);
    }

    // ---- inline compact: 64-lane shuffle inclusive scan + cross-wave scan
    int m = 0;
    m += (av.x != 0.f) ? 1 : 0;
    m += (av.y != 0.f) ? 1 : 0;
    m += (av.z != 0.f) ? 1 : 0;
    m += (av.w != 0.f) ? 1 : 0;
    int sc = m;
    #pragma unroll
    for (int d = 1; d < 64; d <<= 1){
        int t = __shfl_up(sc, d, 64);
        sc += (lane >= d) ? t : 0;
    }
    if (lane == 63) wsum[wave] = sc;
    __syncthreads();
    int base = 0;
    #pragma unroll
    for (int w = 0; w < 4; w++) base += (w < wave) ? wsum[w] : 0;
    int c1 = wsum[0] + wsum[1] + wsum[2] + wsum[3];
    int pos = base + sc - m;
    // write directly to LDS (no runtime-indexed local array -> no scratch)
    {
        int pp = pos;
        if (av.x != 0.f) lidx[pp++] = (unsigned short)(b0);
        if (av.y != 0.f) lidx[pp++] = (unsigned short)(b0 + 1);
        if (av.z != 0.f) lidx[pp++] = (unsigned short)(b0 + 2);
        if (av.w != 0.f) lidx[pp++] = (unsigned short)(b0 + 3);
    }
    __syncthreads();                        // lidx[0..c1) visible
    int npad = (c1 + 63) & ~63;
    if (c1 > 0){
        unsigned short last = lidx[c1 - 1];
        for (int i = c1 + tid; i < npad; i += 256) lidx[i] = last;
    }
    __syncthreads();                        // padding visible

    // In-flight data for 2 x 64-row sub-chunks x 2 m-tiles (register path)
    float4 e0[2][2], e1[2][2]; bf16x8 h0[2][2], h1[2][2];

    auto loadsub = [&](int p, int sub){
        #pragma unroll
        for (int mt = 0; mt < 2; mt++){
            int r = lidx[p + mh*32 + mt*16 + col] & (NN - 1);
            const float* ep = E + ((size_t)a*NN + r)*FE + quad*8;
            e0[sub][mt] = *(const float4*)(ep);
            e1[sub][mt] = *(const float4*)(ep + 4);
            h0[sub][mt] = ldfrag(Hb + r*FN + quad*8);
            h1[sub][mt] = ldfrag(Hb + r*FN + 32 + quad*8);
        }
    };

    auto compsub = [&](int p, int sub){
        bool full = (p + 64) <= c1;
        #pragma unroll
        for (int mt = 0; mt < 2; mt++){
            int4 pk;
            pk.x = (int)packtrunc(e0[sub][mt].x, e0[sub][mt].y);
            pk.y = (int)packtrunc(e0[sub][mt].z, e0[sub][mt].w);
            pk.z = (int)packtrunc(e1[sub][mt].x, e1[sub][mt].y);
            pk.w = (int)packtrunc(e1[sub][mt].z, e1[sub][mt].w);
            bf16x8 ef = __builtin_bit_cast(bf16x8, pk);
            #pragma unroll
            for (int tl = 0; tl < 2; tl++){
                __builtin_amdgcn_s_setprio(1);
                f32x4 pw = __builtin_amdgcn_mfma_f32_16x16x32_bf16(ef, Bw[tl][2],
                           __builtin_amdgcn_mfma_f32_16x16x32_bf16(h1[sub][mt], Bw[tl][1],
                           __builtin_amdgcn_mfma_f32_16x16x32_bf16(h0[sub][mt], Bw[tl][0],
                               cw[tl], 0,0,0), 0,0,0), 0,0,0);
                f32x4 pa = __builtin_amdgcn_mfma_f32_16x16x32_bf16(ef, Ba[tl][2],
                           __builtin_amdgcn_mfma_f32_16x16x32_bf16(h1[sub][mt], Ba[tl][1],
                           __builtin_amdgcn_mfma_f32_16x16x32_bf16(h0[sub][mt], Ba[tl][0],
                               ca[tl], 0,0,0), 0,0,0), 0,0,0);
                __builtin_amdgcn_s_setprio(0);
                if (full){
                    #pragma unroll
                    for (int r = 0; r < 4; r++)
                        acc[tl] += fmaxf(pw[r], 0.f) * fast_sigmoid(pa[r]);
                } else {
                    #pragma unroll
                    for (int r = 0; r < 4; r++){
                        int ps = p + mh*32 + mt*16 + quad*4 + r;
                        float f = fmaxf(pw[r], 0.f) * fast_sigmoid(pa[r]);
                        acc[tl] += (ps < c1) ? f : 0.f;
                    }
                }
            }
        }
    };

    // ---- software-pipelined main loop: sub i's loads issued at i-2/i-1,
    // always >= one full compsub of latency hiding; no cold stalls.
    int nsub = npad >> 6;
    if (nsub > 0){
        loadsub(0, 0);
        if (nsub > 1) loadsub(64, 1);
        for (int i = 0; i < nsub; i++){
            compsub(i << 6, i & 1);
            int nx = i + 2;
            if (nx < nsub) loadsub(nx << 6, i & 1);  // refill just-freed buffer
        }
    }

    #pragma unroll
    for (int tl = 0; tl < 2; tl++)
        red[(wave*4 + quad)*FN + (2*half + tl)*16 + col] = acc[tl];
    __syncthreads();
    if (tid < FN){
        int rbase = (tid >= 32) ? 8 : 0;   // waves 0,1: j<32; waves 2,3: j>=32
        float sum = 0.f;
        #pragma unroll
        for (int r = 0; r < 8; r++) sum += red[(rbase + r)*FN + tid];
        float bj = bias[tid];
        float g0 = fmaxf(bj, 0.f) * fast_sigmoid(bj);
        out[(size_t)a*FN + tid] = sum + (float)(NN - c1) * g0;
    }
}

extern "C" void kernel_launch(void* const* d_in, const int* in_sizes, int n_in,
                              void* d_out, int out_size, void* d_ws, size_t ws_size,
                              hipStream_t stream) {
    const float* H    = (const float*)d_in[0];
    const float* A    = (const float*)d_in[1];
    const float* E    = (const float*)d_in[2];
    const float* W    = (const float*)d_in[3];
    const float* Wa   = (const float*)d_in[4];
    const float* bias = (const float*)d_in[5];
    float* out = (float*)d_out;

    unsigned short* Hb   = (unsigned short*)d_ws;         // 1024*64 bf16
    unsigned short* WtE  = Hb + NN*FN;                    // 64*160
    unsigned short* WtA  = WtE + FN*FIN;                  // 64*160

    prep     <<<dim3(66), dim3(256), 0, stream>>>(H, W, Wa, Hb, WtE, WtA);
    mga_fused<<<dim3(NN), dim3(256), 0, stream>>>(A, E, Hb, WtE, WtA, bias, out);
}

// Round 3
// 224.816 us; speedup vs baseline: 2.1416x; 2.1416x over previous
//
#include <hip/hip_runtime.h>

// N=1024, F_NODE=64, F_EDGE=32, F_IN=160.
// out[a,j] = sum_b gated(a,b,j);  gated = relu(Hp)*sigmoid(Ha)
// Hp[a,b,j] = A[a,b]*(H[a]·W[0:64,j] + H[b]·W[64:128,j] + E[a,b]·W[128:160,j]) + bias[j]
// A in {0,1}: A=0 pairs contribute g0[j]=relu(bias)*sigmoid(bias) (constant).
//
// R11 (this round): fix R10's rule-#20 regression, keep the pipeline.
//  - R10 indexed the in-flight register buffers with runtime `i & 1`
//    -> compiler demoted e0/e1/h0/h1 to scratch (VGPR 84, WRITE_SIZE
//    160 MB of scratch traffic, 327 us). Registers MUST be statically
//    indexed.
//  - Same schedule, unrolled x2 so every buffer index is a literal:
//    steady state: comp(i,b0) -> load(i+2,b0) -> comp(i+1,b1) -> load(i+3,b1).
//    Every sub's loads are issued one full compsub before consumption.
//  - setprio kept; everything else (inline compact, MFMA structure,
//    reduction) is R9's verified structure.
#define NN 1024
#define FN 64
#define FE 32
#define FIN 160

typedef __bf16 bf16x8 __attribute__((ext_vector_type(8)));
typedef short  short8 __attribute__((ext_vector_type(8)));
typedef float  f32x4  __attribute__((ext_vector_type(4)));

static __device__ __forceinline__ unsigned short f2b(float x){
    unsigned int u = __float_as_uint(x);
    unsigned int r = (u + 0x7fffu + ((u >> 16) & 1u)) >> 16;
    return (unsigned short)r;
}

static __device__ __forceinline__ float fast_sigmoid(float y){
    return __builtin_amdgcn_rcpf(1.0f + __expf(-y));
}

static __device__ __forceinline__ bf16x8 ldfrag(const unsigned short* p){
    return __builtin_bit_cast(bf16x8, *(const short8*)(p));
}

// pack two f32 -> (bf16 lo, bf16 hi) by truncation: one v_perm_b32
static __device__ __forceinline__ unsigned packtrunc(float lo, float hi){
    return __builtin_amdgcn_perm(__float_as_uint(hi), __float_as_uint(lo), 0x07060302u);
}

// blocks 0..63: H f32 -> Hb bf16 (1024x64); block 64/65: W/Wa -> Wt[j][k] bf16
__global__ void prep(const float* __restrict__ H, const float* __restrict__ W,
                     const float* __restrict__ Wa,
                     unsigned short* __restrict__ Hb,
                     unsigned short* __restrict__ WtE,
                     unsigned short* __restrict__ WtA){
    int bid = blockIdx.x, tid = threadIdx.x;
    if (bid < 64){
        int i = (bid*256 + tid)*4;
        float4 v = *(const float4*)(H + i);
        ushort4 o;
        o.x = f2b(v.x); o.y = f2b(v.y); o.z = f2b(v.z); o.w = f2b(v.w);
        *(ushort4*)(Hb + i) = o;
    } else {
        const float* src = (bid == 64) ? W : Wa;
        unsigned short* dst = (bid == 64) ? WtE : WtA;
        for (int idx = tid; idx < FIN*FN; idx += 256){
            int k = idx >> 6, j = idx & 63;
            dst[j*FIN + k] = f2b(src[idx]);
        }
    }
}

// One block per row a. Inline compaction (order-preserving shuffle scan into
// LDS), then the pipelined MFMA loop over the compacted list, then direct
// out[a,:] write including the (N-c1)*g0 constant term.
// 4 waves, wave=(half<<1)|mh: half -> j-tiles {2half,2half+1}, mh -> 32-row
// half of each 64-row sub-chunk.
// mfma_f32_16x16x32_bf16: A[m=lane&15][k=quad*8+i], B[k][n=lane&15],
// D: col=lane&15, row=quad*4+reg  [measured m89/m91].
__global__ __launch_bounds__(256, 3) void mga_fused(
    const float* __restrict__ A,
    const float* __restrict__ E,
    const unsigned short* __restrict__ Hb,
    const unsigned short* __restrict__ WtE, const unsigned short* __restrict__ WtA,
    const float* __restrict__ bias, float* __restrict__ out)
{
    int a    = blockIdx.x;
    int tid  = threadIdx.x;
    int wave = tid >> 6, lane = tid & 63;
    int col  = lane & 15, quad = lane >> 4;
    int half = wave >> 1, mh = wave & 1;

    __shared__ unsigned short lidx[NN];    // compacted b-indices, sorted
    __shared__ float red[16*FN];
    __shared__ int wsum[4];

    // ---- issue A-row load first: latency hides under B-frags + init MFMAs
    int b0 = wave*256 + lane*4;
    float4 av = *(const float4*)(A + (size_t)a*NN + b0);

    // Held B-frags: k-segs {64..96,96..128,128..160} x 2 j-tiles x 2 mats
    bf16x8 Bw[2][3], Ba[2][3];
    #pragma unroll
    for (int tl = 0; tl < 2; tl++){
        int n = (2*half + tl)*16 + col;
        #pragma unroll
        for (int sg = 0; sg < 3; sg++){
            Bw[tl][sg] = ldfrag(WtE + n*FIN + (sg+2)*32 + quad*8);
            Ba[tl][sg] = ldfrag(WtA + n*FIN + (sg+2)*32 + quad*8);
        }
    }

    // Upfront c-init = bias[j] + H[a]·W[0:64,j] via broadcast-A MFMAs
    bf16x8 ha0 = ldfrag(Hb + a*FN + quad*8);
    bf16x8 ha1 = ldfrag(Hb + a*FN + 32 + quad*8);
    f32x4 cw[2], ca[2];
    float acc[2] = {0.f, 0.f};
    #pragma unroll
    for (int tl = 0; tl < 2; tl++){
        int n = (2*half + tl)*16 + col;
        float bj = bias[n];
        f32x4 cb = {bj, bj, bj, bj};
        bf16x8 w0 = ldfrag(WtE + n*FIN + quad*8);
        bf16x8 w1 = ldfrag(WtE + n*FIN + 32 + quad*8);
        cw[tl] = __builtin_amdgcn_mfma_f32_16x16x32_bf16(ha1, w1,
                 __builtin_amdgcn_mfma_f32_16x16x32_bf16(ha0, w0, cb, 0,0,0), 0,0,0);
        w0 = ldfrag(WtA + n*FIN + quad*8);
        w1 = ldfrag(WtA + n*FIN + 32 + quad*8);
        ca[tl] = __builtin_amdgcn_mfma_f32_16x16x32_bf16(ha1, w1,
                 __builtin_amdgcn_mfma_f32_16x16x32_bf16(ha0, w0, cb, 0,0,0), 0,0,0);
    }

    // ---- inline compact: 64-lane shuffle inclusive scan + cross-wave scan
    int m = 0;
    m += (av.x != 0.f) ? 1 : 0;
    m += (av.y != 0.f) ? 1 : 0;
    m += (av.z != 0.f) ? 1 : 0;
    m += (av.w != 0.f) ? 1 : 0;
    int sc = m;
    #pragma unroll
    for (int d = 1; d < 64; d <<= 1){
        int t = __shfl_up(sc, d, 64);
        sc += (lane >= d) ? t : 0;
    }
    if (lane == 63) wsum[wave] = sc;
    __syncthreads();
    int base = 0;
    #pragma unroll
    for (int w = 0; w < 4; w++) base += (w < wave) ? wsum[w] : 0;
    int c1 = wsum[0] + wsum[1] + wsum[2] + wsum[3];
    int pos = base + sc - m;
    // write directly to LDS (no runtime-indexed local array -> no scratch)
    {
        int pp = pos;
        if (av.x != 0.f) lidx[pp++] = (unsigned short)(b0);
        if (av.y != 0.f) lidx[pp++] = (unsigned short)(b0 + 1);
        if (av.z != 0.f) lidx[pp++] = (unsigned short)(b0 + 2);
        if (av.w != 0.f) lidx[pp++] = (unsigned short)(b0 + 3);
    }
    __syncthreads();                        // lidx[0..c1) visible
    int npad = (c1 + 63) & ~63;
    if (c1 > 0){
        unsigned short last = lidx[c1 - 1];
        for (int i = c1 + tid; i < npad; i += 256) lidx[i] = last;
    }
    __syncthreads();                        // padding visible

    // In-flight data for 2 x 64-row sub-chunks x 2 m-tiles (register path).
    // ALL indices into these arrays are compile-time constants (rule #20).
    float4 e0[2][2], e1[2][2]; bf16x8 h0[2][2], h1[2][2];

    auto loadsub = [&](int p, int sub){
        #pragma unroll
        for (int mt = 0; mt < 2; mt++){
            int r = lidx[p + mh*32 + mt*16 + col] & (NN - 1);
            const float* ep = E + ((size_t)a*NN + r)*FE + quad*8;
            e0[sub][mt] = *(const float4*)(ep);
            e1[sub][mt] = *(const float4*)(ep + 4);
            h0[sub][mt] = ldfrag(Hb + r*FN + quad*8);
            h1[sub][mt] = ldfrag(Hb + r*FN + 32 + quad*8);
        }
    };

    auto compsub = [&](int p, int sub){
        bool full = (p + 64) <= c1;
        #pragma unroll
        for (int mt = 0; mt < 2; mt++){
            int4 pk;
            pk.x = (int)packtrunc(e0[sub][mt].x, e0[sub][mt].y);
            pk.y = (int)packtrunc(e0[sub][mt].z, e0[sub][mt].w);
            pk.z = (int)packtrunc(e1[sub][mt].x, e1[sub][mt].y);
            pk.w = (int)packtrunc(e1[sub][mt].z, e1[sub][mt].w);
            bf16x8 ef = __builtin_bit_cast(bf16x8, pk);
            #pragma unroll
            for (int tl = 0; tl < 2; tl++){
                __builtin_amdgcn_s_setprio(1);
                f32x4 pw = __builtin_amdgcn_mfma_f32_16x16x32_bf16(ef, Bw[tl][2],
                           __builtin_amdgcn_mfma_f32_16x16x32_bf16(h1[sub][mt], Bw[tl][1],
                           __builtin_amdgcn_mfma_f32_16x16x32_bf16(h0[sub][mt], Bw[tl][0],
                               cw[tl], 0,0,0), 0,0,0), 0,0,0);
                f32x4 pa = __builtin_amdgcn_mfma_f32_16x16x32_bf16(ef, Ba[tl][2],
                           __builtin_amdgcn_mfma_f32_16x16x32_bf16(h1[sub][mt], Ba[tl][1],
                           __builtin_amdgcn_mfma_f32_16x16x32_bf16(h0[sub][mt], Ba[tl][0],
                               ca[tl], 0,0,0), 0,0,0), 0,0,0);
                __builtin_amdgcn_s_setprio(0);
                if (full){
                    #pragma unroll
                    for (int r = 0; r < 4; r++)
                        acc[tl] += fmaxf(pw[r], 0.f) * fast_sigmoid(pa[r]);
                } else {
                    #pragma unroll
                    for (int r = 0; r < 4; r++){
                        int ps = p + mh*32 + mt*16 + quad*4 + r;
                        float f = fmaxf(pw[r], 0.f) * fast_sigmoid(pa[r]);
                        acc[tl] += (ps < c1) ? f : 0.f;
                    }
                }
            }
        }
    };

    // ---- software-pipelined main loop, unrolled x2 -> static buffer idx.
    // Steady state: comp(i,B0); load(i+2,B0); comp(i+1,B1); load(i+3,B1).
    // Every sub's loads are in flight >= one full compsub before use.
    int nsub = npad >> 6;
    if (nsub > 0){
        loadsub(0, 0);
        if (nsub > 1) loadsub(64, 1);
        int i = 0;
        for (; i + 2 <= nsub; i += 2){
            compsub(i << 6, 0);
            if (i + 2 < nsub) loadsub((i + 2) << 6, 0);
            compsub((i + 1) << 6, 1);
            if (i + 3 < nsub) loadsub((i + 3) << 6, 1);
        }
        if (i < nsub) compsub(i << 6, 0);   // odd tail (buffer 0 holds it)
    }

    #pragma unroll
    for (int tl = 0; tl < 2; tl++)
        red[(wave*4 + quad)*FN + (2*half + tl)*16 + col] = acc[tl];
    __syncthreads();
    if (tid < FN){
        int rbase = (tid >= 32) ? 8 : 0;   // waves 0,1: j<32; waves 2,3: j>=32
        float sum = 0.f;
        #pragma unroll
        for (int r = 0; r < 8; r++) sum += red[(rbase + r)*FN + tid];
        float bj = bias[tid];
        float g0 = fmaxf(bj, 0.f) * fast_sigmoid(bj);
        out[(size_t)a*FN + tid] = sum + (float)(NN - c1) * g0;
    }
}

extern "C" void kernel_launch(void* const* d_in, const int* in_sizes, int n_in,
                              void* d_out, int out_size, void* d_ws, size_t ws_size,
                              hipStream_t stream) {
    const float* H    = (const float*)d_in[0];
    const float* A    = (const float*)d_in[1];
    const float* E    = (const float*)d_in[2];
    const float* W    = (const float*)d_in[3];
    const float* Wa   = (const float*)d_in[4];
    const float* bias = (const float*)d_in[5];
    float* out = (float*)d_out;

    unsigned short* Hb   = (unsigned short*)d_ws;         // 1024*64 bf16
    unsigned short* WtE  = Hb + NN*FN;                    // 64*160
    unsigned short* WtA  = WtE + FN*FIN;                  // 64*160

    prep     <<<dim3(66), dim3(256), 0, stream>>>(H, W, Wa, Hb, WtE, WtA);
    mga_fused<<<dim3(NN), dim3(256), 0, stream>>>(A, E, Hb, WtE, WtA, bias, out);
}